// Round 6
// baseline (270.018 us; speedup 1.0000x reference)
//
#include <hip/hip_runtime.h>
#include <stdint.h>

// Problem constants (fixed shapes from reference)
#define M_DIM 4096   // 2 * 2048 rows of x
#define K_DIM 4096   // in_features
#define N_DIM 4096   // out_features
#define KT    64     // K tiles of 64 bytes (i8) per row

typedef float f32x4 __attribute__((ext_vector_type(4)));
typedef int   i32x4 __attribute__((ext_vector_type(4)));

// ---------------------------------------------------------------------------
// Fragment-major tiled layout for i8 operands (both xq and wq):
//   row R, k-byte Kb  ->  tile (g = R>>4, c = Kb>>6), slot = (q*16 + r),
//   where r = R&15, q = (Kb>>4)&3, byte b = Kb&15.
//   offset = (g*KT + c)*1024 + slot*16 + b.
// A wave's MFMA fragment load (lane = q*16 + r) is then base + lane*16 —
// 1 KB fully-coalesced global_load_dwordx4 straight into registers.
// ---------------------------------------------------------------------------

// ---------------------------------------------------------------------------
// Kernel 1: x fp32 -> i8 per-row scale, stored in fragment-major layout.
// One block per row; thread t handles k = t*16..t*16+15.
// ---------------------------------------------------------------------------
__global__ __launch_bounds__(256) void quant_x(const float* __restrict__ x,
                                               int8_t* __restrict__ xq,
                                               float* __restrict__ sx) {
    __shared__ float red[4];
    const int row  = blockIdx.x;
    const int t    = threadIdx.x;
    const float* xr = x + (size_t)row * K_DIM + t * 16;
    float4 v[4];
#pragma unroll
    for (int c = 0; c < 4; ++c) v[c] = ((const float4*)xr)[c];
    float am = 0.f;
#pragma unroll
    for (int c = 0; c < 4; ++c) {
        am = fmaxf(am, fabsf(v[c].x)); am = fmaxf(am, fabsf(v[c].y));
        am = fmaxf(am, fabsf(v[c].z)); am = fmaxf(am, fabsf(v[c].w));
    }
#pragma unroll
    for (int off = 32; off; off >>= 1) am = fmaxf(am, __shfl_xor(am, off, 64));
    if ((t & 63) == 0) red[t >> 6] = am;
    __syncthreads();
    float amax = fmaxf(fmaxf(red[0], red[1]), fmaxf(red[2], red[3]));
    amax = fmaxf(amax, 1e-20f);
    const float inv = 127.0f / amax;
    int ow[4];
#pragma unroll
    for (int c = 0; c < 4; ++c) {
        int q0 = __float2int_rn(v[c].x * inv);
        int q1 = __float2int_rn(v[c].y * inv);
        int q2 = __float2int_rn(v[c].z * inv);
        int q3 = __float2int_rn(v[c].w * inv);
        ow[c] = (q0 & 255) | ((q1 & 255) << 8) | ((q2 & 255) << 16) | ((q3 & 255) << 24);
    }
    // swizzled destination: tile (row>>4, t>>2), slot ((t&3)*16 + row&15)
    const size_t off = (((size_t)(row >> 4) * KT + (t >> 2)) << 10)
                     + (((t & 3) << 4) + (row & 15)) * 16;
    ((int4*)(xq + off))[0] = make_int4(ow[0], ow[1], ow[2], ow[3]);
    if (t == 0) sx[row] = amax / 127.0f;
}

// ---------------------------------------------------------------------------
// Kernel 2: Q4_K dequant -> i8 W per-row scale, fragment-major layout.
// One block per W-row. w = q*a + b (a,b>=0) => exact row max = max(15a+b).
// ---------------------------------------------------------------------------
__global__ __launch_bounds__(256) void quant_w(const int* __restrict__ packed,
                                               const float* __restrict__ d,
                                               const float* __restrict__ dmin,
                                               const int* __restrict__ scales,
                                               const int* __restrict__ mins,
                                               int8_t* __restrict__ wq,
                                               float* __restrict__ sw) {
    __shared__ float sa[128], sb[128], red[4];
    const int n = blockIdx.x;
    const int t = threadIdx.x;
    float m = 0.f;
    if (t < 128) {
        int sub  = n * 128 + t;
        int sidx = n * 16 + (t >> 3);
        float dd = d[sidx], dm = dmin[sidx];
        float a = dd * (float)scales[sub] * (1.0f / 945.0f);
        float b = dd * (float)mins[sub] * (1.0f / 63.0f) + dm;
        sa[t] = a; sb[t] = b;
        m = 15.0f * a + b;
    }
#pragma unroll
    for (int off = 32; off; off >>= 1) m = fmaxf(m, __shfl_xor(m, off, 64));
    if ((t & 63) == 0) red[t >> 6] = m;
    __syncthreads();
    float rowmax = fmaxf(fmaxf(red[0], red[1]), fmaxf(red[2], red[3]));
    rowmax = fmaxf(rowmax, 1e-20f);
    const float inv = 127.0f / rowmax;

    const int sub = t >> 1;                    // 16 weights = half a subblock
    const float a = sa[sub] * inv;
    const float b = sb[sub] * inv;
    const int4* p4 = (const int4*)(packed + (size_t)n * (K_DIM / 2) + t * 8);
    int4 pv0 = p4[0], pv1 = p4[1];
    int bytes[8] = {pv0.x, pv0.y, pv0.z, pv0.w, pv1.x, pv1.y, pv1.z, pv1.w};
    int ow[4];
#pragma unroll
    for (int c = 0; c < 4; ++c) {
        int b0 = bytes[2 * c], b1 = bytes[2 * c + 1];
        int q0 = __float2int_rn((float)(b0 & 15) * a + b);
        int q1 = __float2int_rn((float)((b0 >> 4) & 15) * a + b);
        int q2 = __float2int_rn((float)(b1 & 15) * a + b);
        int q3 = __float2int_rn((float)((b1 >> 4) & 15) * a + b);
        ow[c] = (q0 & 255) | ((q1 & 255) << 8) | ((q2 & 255) << 16) | ((q3 & 255) << 24);
    }
    const size_t off = (((size_t)(n >> 4) * KT + (t >> 2)) << 10)
                     + (((t & 3) << 4) + (n & 15)) * 16;
    ((int4*)(wq + off))[0] = make_int4(ow[0], ow[1], ow[2], ow[3]);
    if (t == 0) sw[n] = rowmax / 127.0f;
}

// ---------------------------------------------------------------------------
// Kernel 3: C = sx[m]*sw[n] * (Aq . Bq^T), i8 16x16x64 MFMA.
// LDS-FREE: operands are pre-tiled fragment-major, so each fragment is one
// perfectly-coalesced global_load_dwordx4 (base + lane*16) straight into
// VGPRs. No barriers anywhere in the K-loop; distance-1 ping-pong prefetch
// lets the compiler interleave MFMA and VMEM with fine-grained vmcnt
// (the AITER property the 2-barrier LDS structure could not express).
// Per iter: 8 x 1KB coalesced loads + 16 MFMAs.
// ---------------------------------------------------------------------------
__global__ __launch_bounds__(256) void gemm_i8(const int8_t* __restrict__ A,
                                               const int8_t* __restrict__ B,
                                               const float* __restrict__ sx,
                                               const float* __restrict__ sw,
                                               float* __restrict__ C) {
    const int tid  = threadIdx.x;
    const int wave = tid >> 6;
    const int lane = tid & 63;
    const int wm = wave >> 1;
    const int wn = wave & 1;
    const int r = lane & 15;
    const int q = lane >> 4;

    // XCD-aware swizzle (kept; neutral but harmless)
    const int bid  = blockIdx.x;
    const int xcd  = bid & 7;
    const int slot = bid >> 3;
    const int m0 = (((xcd >> 2) << 4) + (slot & 15)) * 128;
    const int n0 = (((xcd & 3) << 3) + (slot >> 4)) * 128;

    // Fragment bases: row-group gA+t holds rows m0+wm*64+t*16 .. +15.
    const int gA = (m0 >> 4) + wm * 4;
    const int gB = (n0 >> 4) + wn * 4;
    const int8_t* pA = A + ((size_t)gA * KT << 10) + lane * 16;
    const int8_t* pB = B + ((size_t)gB * KT << 10) + lane * 16;

    i32x4 acc[4][4] = {};
    i32x4 a0[4], b0[4], a1[4], b1[4];

#define LOADF(fa, fb, i)                                                   \
    do {                                                                   \
        _Pragma("unroll")                                                  \
        for (int tt = 0; tt < 4; ++tt) {                                   \
            fa[tt] = *(const i32x4*)(pA + ((size_t)(tt * KT + (i)) << 10));\
            fb[tt] = *(const i32x4*)(pB + ((size_t)(tt * KT + (i)) << 10));\
        }                                                                  \
    } while (0)

#define MFMA(fa, fb)                                                       \
    do {                                                                   \
        _Pragma("unroll")                                                  \
        for (int ii = 0; ii < 4; ++ii)                                     \
            _Pragma("unroll")                                              \
            for (int jj = 0; jj < 4; ++jj)                                 \
                acc[ii][jj] = __builtin_amdgcn_mfma_i32_16x16x64_i8(       \
                    fa[ii], fb[jj], acc[ii][jj], 0, 0, 0);                 \
    } while (0)

    LOADF(a0, b0, 0);
#pragma unroll 1
    for (int i = 0; i < 31; ++i) {
        LOADF(a1, b1, 2 * i + 1);    // prefetch odd tile
        MFMA(a0, b0);                // compute even tile
        LOADF(a0, b0, 2 * i + 2);    // prefetch next even tile
        MFMA(a1, b1);                // compute odd tile
    }
    LOADF(a1, b1, 63);
    MFMA(a0, b0);
    MFMA(a1, b1);
#undef LOADF
#undef MFMA

    // Epilogue: C/D layout col = lane&15, row = (lane>>4)*4 + reg  [m89]
#pragma unroll
    for (int fi = 0; fi < 4; ++fi) {
        int row = m0 + wm * 64 + fi * 16 + q * 4;
#pragma unroll
        for (int fj = 0; fj < 4; ++fj) {
            int col = n0 + wn * 64 + fj * 16 + r;
            float swc = sw[col];
#pragma unroll
            for (int reg = 0; reg < 4; ++reg)
                C[(size_t)(row + reg) * N_DIM + col] =
                    (float)acc[fi][fj][reg] * sx[row + reg] * swc;
        }
    }
}

// ---------------------------------------------------------------------------
// Launch: ws usage = 16.7 MB xq + 16.7 MB wq + 32 KB scales.
// ---------------------------------------------------------------------------
extern "C" void kernel_launch(void* const* d_in, const int* in_sizes, int n_in,
                              void* d_out, int out_size, void* d_ws, size_t ws_size,
                              hipStream_t stream) {
    const float* x      = (const float*)d_in[0];
    const int*   packed = (const int*)d_in[1];
    const float* d      = (const float*)d_in[2];
    const float* dmin   = (const float*)d_in[3];
    const int*   scales = (const int*)d_in[4];
    const int*   mins   = (const int*)d_in[5];
    float* out = (float*)d_out;

    int8_t* xq = (int8_t*)d_ws;                               // 16.7 MB
    int8_t* wq = xq + (size_t)M_DIM * K_DIM;                  // 16.7 MB
    float*  sx = (float*)(wq + (size_t)N_DIM * K_DIM);        // 16 KB
    float*  sw = sx + M_DIM;                                  // 16 KB

    quant_x<<<M_DIM, 256, 0, stream>>>(x, xq, sx);
    quant_w<<<N_DIM, 256, 0, stream>>>(packed, d, dmin, scales, mins, wq, sw);
    gemm_i8<<<1024, 256, 0, stream>>>(xq, wq, sx, sw, out);
}